// Round 8
// baseline (191.982 us; speedup 1.0000x reference)
//
#include <hip/hip_runtime.h>
#include <hip/hip_cooperative_groups.h>

namespace cg = cooperative_groups;

typedef unsigned short u16;
typedef unsigned int u32;

typedef __bf16 bf16x8 __attribute__((ext_vector_type(8)));
typedef float f32x4 __attribute__((ext_vector_type(4)));

__device__ __forceinline__ u16 f2bf(float f) {
  u32 u = __float_as_uint(f);
  u = u + 0x7fffu + ((u >> 16) & 1u);
  return (u16)(u >> 16);
}
__device__ __forceinline__ float bf2f(u16 u) {
  return __uint_as_float(((u32)u) << 16);
}

// strict-< top-3 insert: distances via min + 2x med3, indices via cmp+cndmask.
__device__ __forceinline__ void ins3m(float d, int s,
                                      float& d0, float& d1, float& d2,
                                      int& i0, int& i1, int& i2) {
  bool c0 = d < d0, c1 = d < d1, c2 = d < d2;
  float n0 = fminf(d, d0);
  float n1 = __builtin_amdgcn_fmed3f(d, d0, d1);
  float n2 = __builtin_amdgcn_fmed3f(d, d1, d2);
  i2 = c1 ? i1 : (c2 ? s : i2);
  i1 = c0 ? i0 : (c1 ? s : i1);
  i0 = c0 ? s : i0;
  d0 = n0; d1 = n1; d2 = n2;
}

// butterfly merge step across sub-lanes: lo-half list stays incumbent.
__device__ __forceinline__ void merge_shfl(int m, int sub,
                                           float& d0, float& d1, float& d2,
                                           int& i0, int& i1, int& i2) {
  float e0 = __shfl_xor(d0, m), e1 = __shfl_xor(d1, m), e2 = __shfl_xor(d2, m);
  int   f0 = __shfl_xor(i0, m), f1 = __shfl_xor(i1, m), f2 = __shfl_xor(i2, m);
  const bool up = (sub & m) != 0;
  float L0 = up ? e0 : d0, L1 = up ? e1 : d1, L2 = up ? e2 : d2;
  int   K0 = up ? f0 : i0, K1 = up ? f1 : i1, K2 = up ? f2 : i2;
  float H0 = up ? d0 : e0, H1 = up ? d1 : e1, H2 = up ? d2 : e2;
  int   G0 = up ? i0 : f0, G1 = up ? i1 : f1, G2 = up ? i2 : f2;
  ins3m(H0, G0, L0, L1, L2, K0, K1, K2);
  ins3m(H1, G1, L0, L1, L2, K0, K1, K2);
  ins3m(H2, G2, L0, L1, L2, K0, K1, K2);
  d0 = L0; d1 = L1; d2 = L2; i0 = K0; i1 = K1; i2 = K2;
}

__device__ __forceinline__ uint4 bnrelu_pack(uint4 raw, const float* a1s, const float* b1s, int kb) {
  union { uint4 v; u16 s[8]; } u;
  u.v = raw;
#pragma unroll
  for (int e = 0; e < 8; ++e) {
    float f = fmaxf(bf2f(u.s[e]) * a1s[kb + e] + b1s[kb + e], 0.f);
    u.s[e] = f2bf(f);
  }
  return u.v;
}

// ---------------------------------------------------------------- weights -> bf16 fragment order + S2 precompute + zero banked stats
__global__ __launch_bounds__(256) void conv_w_kernel(
    const float* __restrict__ W1, const float* __restrict__ W2,
    const float* __restrict__ sxyz, u16* __restrict__ W1f,
    u16* __restrict__ W2f, float4* __restrict__ S2,
    float* __restrict__ stats) {
  int i = blockIdx.x * 256 + threadIdx.x;      // 512 * 256 = 131072 exactly
  if (i < 98304) {
    int e = i & 7, l = (i >> 3) & 63, g = (i >> 9) & 15, kt = i >> 13;
    int col = g * 16 + (l & 15);
    int k = kt * 32 + (l >> 4) * 8 + e;
    W1f[i] = f2bf(W1[col * 384 + k]);
  } else {
    int j = i - 98304;
    int e = j & 7, l = (j >> 3) & 63, g = (j >> 9) & 7, kt = j >> 12;
    int col = g * 16 + (l & 15);
    int k = kt * 32 + (l >> 4) * 8 + e;
    W2f[j] = f2bf(W2[col * 256 + k]);
  }
  if (i < 16384) {
    float x = sxyz[i * 3 + 0], y = sxyz[i * 3 + 1], z = sxyz[i * 3 + 2];
    float r2 = __fadd_rn(__fadd_rn(__fmul_rn(x, x), __fmul_rn(y, y)), __fmul_rn(z, z));
    S2[i] = make_float4(x + x, y + y, z + z, r2);
  }
  if (i < 6144) stats[i] = 0.f;
}

// ---------------------------------------------------------------- COOPERATIVE MEGA-KERNEL: 3NN+gather+GEMM1 | sync | BN1+GEMM2 | sync | BN2+out
// 2048 blocks x 256 threads, 8 blocks/CU co-resident (LDS 19456B, VGPR<=64).
// Y1 tile lives in LDS across sync1; gemm2 acc lives in registers across sync2.
// Eliminates: Y1 global round-trip (66MB), out f32 round-trip (66MB), 2 launches.
__global__ __launch_bounds__(256, 8) void mega_kernel(
    const float* __restrict__ txyz, const float4* __restrict__ S2,
    const float* __restrict__ sfeat, const float* __restrict__ skip,
    const u16* __restrict__ W1f, const u16* __restrict__ W2f,
    const float* __restrict__ g1, const float* __restrict__ be1,
    const float* __restrict__ g2, const float* __restrict__ be2,
    float* __restrict__ out, float* __restrict__ stats1,
    float* __restrict__ stats2) {
  // LDS overlays (19456B total):
  //  [0..17408): sP float4[1040] (scan) -> As 32x264 u16 (gemm1 A, feat cols only)
  //              -> As2 32x272 u16 (Y1 tile, phase A epilogue .. phase B)
  //  [17408..18432): nnbuf4[64] (phase A) -> a1s[256] (phase B) -> a2s/b2s[128+128] (phase C)
  //  [18432..19456): b1s[256] (phase B) / csq reuse
  __shared__ __align__(16) char smem[19456];
  float4* sP     = (float4*)smem;
  u16*    As     = (u16*)smem;
  u16*    As2    = (u16*)smem;
  float4* nnbuf4 = (float4*)(smem + 17408);
  float*  a1s    = (float*)(smem + 17408);
  float*  b1s    = (float*)(smem + 18432);
  float*  csum   = (float*)(smem + 17408);     // reuse a1s after bn pass
  float*  csq    = (float*)(smem + 18432);     // reuse b1s after bn pass
  float*  a2s    = (float*)(smem + 17408);     // post-sync2
  float*  b2s    = (float*)(smem + 17920);

  const int t = threadIdx.x;
  const int raw = blockIdx.x;
  const int logical = (raw & 7) * 256 + (raw >> 3);   // bijective XCD swizzle
  const int b = logical >> 7;
  const int pg = logical & 127;
  const size_t n0 = (size_t)b * 4096 + (size_t)pg * 32;
  const int w = t >> 6, l = t & 63;
  const int lm = l & 15, q = l >> 4;

  // ===== phase A0: (2x,2y,2z,r2) into LDS
  const float4* s2b = S2 + (size_t)b * 1024;
  for (int i = t; i < 1024; i += 256)
    sP[i + (i >> 6)] = s2b[i];
  __syncthreads();

  // ===== phase A1: 3NN scan (2 pts/thread x 16 sub-scans of 64; dual streams)
  {
    const int pp = t >> 4, sub = t & 15;
    const float* ta = txyz + (n0 + pp * 2) * 3;
    const float a0 = ta[0], a1 = ta[1], a2 = ta[2];
    const float b0 = ta[3], b1 = ta[4], b2 = ta[5];
    const float q2a = __fadd_rn(__fadd_rn(__fmul_rn(a0, a0), __fmul_rn(a1, a1)), __fmul_rn(a2, a2));
    const float q2b = __fadd_rn(__fadd_rn(__fmul_rn(b0, b0), __fmul_rn(b1, b1)), __fmul_rn(b2, b2));

    float dA0 = 1e30f, dA1 = 1e30f, dA2 = 1e30f; int iA0 = 0, iA1 = 0, iA2 = 0;
    float dB0 = 1e30f, dB1 = 1e30f, dB2 = 1e30f; int iB0 = 0, iB1 = 0, iB2 = 0;
    float dC0 = 1e30f, dC1 = 1e30f, dC2 = 1e30f; int iC0 = 0, iC1 = 0, iC2 = 0;
    float dD0 = 1e30f, dD1 = 1e30f, dD2 = 1e30f; int iD0 = 0, iD1 = 0, iD2 = 0;
    const int sbeg = sub * 64;
    const float4* sA = sP + sbeg + (sbeg >> 6);

#pragma unroll 4
    for (int off = 0; off < 32; ++off) {
      const int s0 = sbeg + off;
      const int s1 = sbeg + 32 + off;
      float4 p0 = sA[off];
      float4 p1 = sA[32 + off];

      float c00 = __fmul_rn(a0, p0.x);
      c00 = __fadd_rn(c00, __fmul_rn(a1, p0.y));
      c00 = __fadd_rn(c00, __fmul_rn(a2, p0.z));
      float d00 = fmaxf(__fadd_rn(__fadd_rn(q2a, p0.w), -c00), 0.0f);

      float c01 = __fmul_rn(a0, p1.x);
      c01 = __fadd_rn(c01, __fmul_rn(a1, p1.y));
      c01 = __fadd_rn(c01, __fmul_rn(a2, p1.z));
      float d01 = fmaxf(__fadd_rn(__fadd_rn(q2a, p1.w), -c01), 0.0f);

      float c10 = __fmul_rn(b0, p0.x);
      c10 = __fadd_rn(c10, __fmul_rn(b1, p0.y));
      c10 = __fadd_rn(c10, __fmul_rn(b2, p0.z));
      float d10 = fmaxf(__fadd_rn(__fadd_rn(q2b, p0.w), -c10), 0.0f);

      float c11 = __fmul_rn(b0, p1.x);
      c11 = __fadd_rn(c11, __fmul_rn(b1, p1.y));
      c11 = __fadd_rn(c11, __fmul_rn(b2, p1.z));
      float d11 = fmaxf(__fadd_rn(__fadd_rn(q2b, p1.w), -c11), 0.0f);

      ins3m(d00, s0, dA0, dA1, dA2, iA0, iA1, iA2);
      ins3m(d01, s1, dB0, dB1, dB2, iB0, iB1, iB2);
      ins3m(d10, s0, dC0, dC1, dC2, iC0, iC1, iC2);
      ins3m(d11, s1, dD0, dD1, dD2, iD0, iD1, iD2);
    }
    ins3m(dB0, iB0, dA0, dA1, dA2, iA0, iA1, iA2);
    ins3m(dB1, iB1, dA0, dA1, dA2, iA0, iA1, iA2);
    ins3m(dB2, iB2, dA0, dA1, dA2, iA0, iA1, iA2);
    ins3m(dD0, iD0, dC0, dC1, dC2, iC0, iC1, iC2);
    ins3m(dD1, iD1, dC0, dC1, dC2, iC0, iC1, iC2);
    ins3m(dD2, iD2, dC0, dC1, dC2, iC0, iC1, iC2);

#pragma unroll
    for (int m = 1; m <= 8; m <<= 1) {
      merge_shfl(m, sub, dA0, dA1, dA2, iA0, iA1, iA2);
      merge_shfl(m, sub, dC0, dC1, dC2, iC0, iC1, iC2);
    }

    if (sub < 2) {
      const float tx = sub ? b0 : a0;
      const float ty = sub ? b1 : a1;
      const float tz = sub ? b2 : a2;
      const int   I0 = sub ? iC0 : iA0;
      const int   I1 = sub ? iC1 : iA1;
      const int   I2 = sub ? iC2 : iA2;
      int idxs[3] = {I0, I1, I2};
      float wv[3], wsum = 0.f;
      for (int k = 0; k < 3; ++k) {
        float4 sp = sP[idxs[k] + (idxs[k] >> 6)];
        float sx = 0.5f * sp.x, sy = 0.5f * sp.y, sz = 0.5f * sp.z;
        float dx = tx - sx, dy = ty - sy, dz = tz - sz;
        float dd = __fadd_rn(__fadd_rn(__fmul_rn(dx, dx), __fmul_rn(dy, dy)), __fmul_rn(dz, dz));
        wv[k] = 1.0f / (dd + 1e-8f);
        wsum += wv[k];
      }
      float inv = 1.0f / wsum;
      const int rr = pp * 2 + sub;
      nnbuf4[rr * 2 + 0] = make_float4(__int_as_float(I0), __int_as_float(I1), __int_as_float(I2), 0.f);
      nnbuf4[rr * 2 + 1] = make_float4(wv[0] * inv, wv[1] * inv, wv[2] * inv, 0.f);
    }
  }
  __syncthreads();   // sP reads done; As may overwrite

  // ===== phase A2: wave-coalesced gather staging (feat cols 0..255 only)
  {
    float4 my = nnbuf4[w * 16 + lm];
    const float4* fb4 = (const float4*)(sfeat + (size_t)b * 1024 * 256);
    const int r0 = w * 8;
#pragma unroll 4
    for (int r = 0; r < 8; ++r) {
      int j0 = __float_as_int(__shfl(my.x, 2 * r));
      int j1 = __float_as_int(__shfl(my.y, 2 * r));
      int j2 = __float_as_int(__shfl(my.z, 2 * r));
      float w0 = __shfl(my.x, 2 * r + 1);
      float w1 = __shfl(my.y, 2 * r + 1);
      float w2 = __shfl(my.z, 2 * r + 1);
      float4 A  = fb4[(size_t)j0 * 64 + l];
      float4 Bv = fb4[(size_t)j1 * 64 + l];
      float4 Cv = fb4[(size_t)j2 * 64 + l];
      ushort4 o;
      o.x = f2bf(w0 * A.x + w1 * Bv.x + w2 * Cv.x);
      o.y = f2bf(w0 * A.y + w1 * Bv.y + w2 * Cv.y);
      o.z = f2bf(w0 * A.z + w1 * Bv.z + w2 * Cv.z);
      o.w = f2bf(w0 * A.w + w1 * Bv.w + w2 * Cv.w);
      *(ushort4*)&As[(r0 + r) * 264 + 4 * l] = o;
    }
  }
  __syncthreads();

  // ===== phase A3: gemm1 K-loop (kt 0..7 from LDS; kt 8..11 skip-direct from global)
  const int wn = w;
  f32x4 acc[2][4] = {};
  const u16* Bf = W1f + (wn * 4) * 512 + l * 8;

#pragma unroll 4
  for (int kt = 0; kt < 8; ++kt) {
    bf16x8 af0 = *(const bf16x8*)&As[(lm) * 264 + kt * 32 + q * 8];
    bf16x8 af1 = *(const bf16x8*)&As[(16 + lm) * 264 + kt * 32 + q * 8];
#pragma unroll
    for (int j = 0; j < 4; ++j) {
      bf16x8 bv = *(const bf16x8*)(Bf + kt * 8192 + j * 512);
      acc[0][j] = __builtin_amdgcn_mfma_f32_16x16x32_bf16(af0, bv, acc[0][j], 0, 0, 0);
      acc[1][j] = __builtin_amdgcn_mfma_f32_16x16x32_bf16(af1, bv, acc[1][j], 0, 0, 0);
    }
  }
#pragma unroll
  for (int kt2 = 0; kt2 < 4; ++kt2) {
    bf16x8 af[2];
#pragma unroll
    for (int i = 0; i < 2; ++i) {
      const float* sk = skip + (n0 + i * 16 + lm) * 128 + kt2 * 32 + q * 8;
      float4 s0 = *(const float4*)(sk);
      float4 s1 = *(const float4*)(sk + 4);
      union { bf16x8 v; u16 s[8]; } u;
      u.s[0] = f2bf(s0.x); u.s[1] = f2bf(s0.y); u.s[2] = f2bf(s0.z); u.s[3] = f2bf(s0.w);
      u.s[4] = f2bf(s1.x); u.s[5] = f2bf(s1.y); u.s[6] = f2bf(s1.z); u.s[7] = f2bf(s1.w);
      af[i] = u.v;
    }
#pragma unroll
    for (int j = 0; j < 4; ++j) {
      bf16x8 bv = *(const bf16x8*)(Bf + (8 + kt2) * 8192 + j * 512);
      acc[0][j] = __builtin_amdgcn_mfma_f32_16x16x32_bf16(af[0], bv, acc[0][j], 0, 0, 0);
      acc[1][j] = __builtin_amdgcn_mfma_f32_16x16x32_bf16(af[1], bv, acc[1][j], 0, 0, 0);
    }
  }
  __syncthreads();   // all As reads done; As2 overlay safe

  // ===== phase A4: Y1 tile -> As2 (bf16) + banked stats1
  {
    float lsum[4] = {0, 0, 0, 0}, lsq[4] = {0, 0, 0, 0};
    const int colb = wn * 64;
#pragma unroll
    for (int i = 0; i < 2; ++i) {
#pragma unroll
      for (int r = 0; r < 4; ++r) {
        const int lrow = i * 16 + q * 4 + r;
#pragma unroll
        for (int j = 0; j < 4; ++j) {
          float v = acc[i][j][r];
          As2[lrow * 272 + colb + j * 16 + lm] = f2bf(v);
          lsum[j] += v; lsq[j] += v * v;
        }
      }
    }
#pragma unroll
    for (int j = 0; j < 4; ++j) {
      lsum[j] += __shfl_xor(lsum[j], 16); lsum[j] += __shfl_xor(lsum[j], 32);
      lsq[j]  += __shfl_xor(lsq[j], 16);  lsq[j]  += __shfl_xor(lsq[j], 32);
    }
    if (q == 0) {
      float* bank = stats1 + (size_t)(raw & 7) * 512;
#pragma unroll
      for (int j = 0; j < 4; ++j) {
        atomicAdd(&bank[colb + j * 16 + lm], lsum[j]);
        atomicAdd(&bank[256 + colb + j * 16 + lm], lsq[j]);
      }
    }
  }

  cg::this_grid().sync();

  // ===== phase B0: bn1 finalize (sum 8 banks) into LDS
  {
    float s = 0.f, sq = 0.f;
#pragma unroll
    for (int k = 0; k < 8; ++k) {
      s += stats1[k * 512 + t];
      sq += stats1[k * 512 + 256 + t];
    }
    const float invN = 1.0f / 65536.0f;
    float mean = s * invN;
    float var = sq * invN - mean * mean;
    float a = g1[t] * rsqrtf(var + 1e-5f);
    a1s[t] = a;
    b1s[t] = be1[t] - mean * a;
  }
  __syncthreads();

  // ===== phase B1: in-place bn1+relu on the Y1 tile
  {
    const int row = t >> 3, cb = (t & 7) * 32;
#pragma unroll
    for (int v = 0; v < 4; ++v) {
      const int kb = cb + v * 8;
      uint4 r4 = *(uint4*)&As2[row * 272 + kb];
      r4 = bnrelu_pack(r4, a1s, b1s, kb);
      *(uint4*)&As2[row * 272 + kb] = r4;
    }
  }
  __syncthreads();

  // ===== phase B2: gemm2 K-loop (acc2 stays in registers through sync2)
  const int wm2 = w >> 1, wn2 = w & 1;
  const int colb2 = wn2 * 64;
  f32x4 acc2[4] = {};
  const u16* Bf2 = W2f + (wn2 * 4) * 512 + l * 8;

#pragma unroll 4
  for (int kt = 0; kt < 8; ++kt) {
    bf16x8 af = *(const bf16x8*)&As2[(wm2 * 16 + lm) * 272 + kt * 32 + q * 8];
#pragma unroll
    for (int j = 0; j < 4; ++j) {
      bf16x8 bv = *(const bf16x8*)(Bf2 + kt * 4096 + j * 512);
      acc2[j] = __builtin_amdgcn_mfma_f32_16x16x32_bf16(af, bv, acc2[j], 0, 0, 0);
    }
  }

  // ===== phase B3: stats2 (shfl -> LDS cells -> banked atomics)
  {
    float ls2[4] = {0, 0, 0, 0}, lq2[4] = {0, 0, 0, 0};
#pragma unroll
    for (int r = 0; r < 4; ++r)
#pragma unroll
      for (int j = 0; j < 4; ++j) {
        float v = acc2[j][r];
        ls2[j] += v; lq2[j] += v * v;
      }
#pragma unroll
    for (int j = 0; j < 4; ++j) {
      ls2[j] += __shfl_xor(ls2[j], 16); ls2[j] += __shfl_xor(ls2[j], 32);
      lq2[j] += __shfl_xor(lq2[j], 16); lq2[j] += __shfl_xor(lq2[j], 32);
    }
    if (q == 0) {
      const int cell = wm2 * 128 + colb2;   // unique per (wm2,wn2,j,lm): plain store
#pragma unroll
      for (int j = 0; j < 4; ++j) {
        csum[cell + j * 16 + lm] = ls2[j];
        csq[cell + j * 16 + lm] = lq2[j];
      }
    }
    __syncthreads();
    if (t < 128) {
      float* bank = stats2 + (size_t)(raw & 7) * 256;
      atomicAdd(&bank[t], csum[t] + csum[128 + t]);
      atomicAdd(&bank[128 + t], csq[t] + csq[128 + t]);
    }
  }

  cg::this_grid().sync();

  // ===== phase C: bn2 finalize + apply to registers + single final write
  if (t < 128) {
    float s = 0.f, sq = 0.f;
#pragma unroll
    for (int k = 0; k < 8; ++k) {
      s += stats2[k * 256 + t];
      sq += stats2[k * 256 + 128 + t];
    }
    const float invN = 1.0f / 65536.0f;
    float mean = s * invN;
    float var = sq * invN - mean * mean;
    float a = g2[t] * rsqrtf(var + 1e-5f);
    a2s[t] = a;
    b2s[t] = be2[t] - mean * a;
  }
  __syncthreads();
#pragma unroll
  for (int r = 0; r < 4; ++r) {
    const size_t grow = n0 + wm2 * 16 + q * 4 + r;
#pragma unroll
    for (int j = 0; j < 4; ++j) {
      const int c = colb2 + j * 16 + lm;
      out[grow * 128 + c] = fmaxf(acc2[j][r] * a2s[c] + b2s[c], 0.f);
    }
  }
}

// ================================================================ FALLBACK PATH (round-7 proven kernels)
__global__ __launch_bounds__(256, 6) void fused1_kernel(
    const float* __restrict__ txyz, const float4* __restrict__ S2,
    const float* __restrict__ sfeat, const float* __restrict__ skip,
    const u16* __restrict__ W1f, u16* __restrict__ Y,
    float* __restrict__ stats1) {
  __shared__ __align__(16) char smem[26624];
  u16*    As     = (u16*)smem;
  float4* sP     = (float4*)smem;
  float4* nnbuf4 = (float4*)(smem + 25600);

  const int t = threadIdx.x;
  const int raw = blockIdx.x;
  const int logical = (raw & 7) * 256 + (raw >> 3);
  const int b = logical >> 7;
  const int pg = logical & 127;
  const size_t n0 = (size_t)b * 4096 + (size_t)pg * 32;

  const float4* s2b = S2 + (size_t)b * 1024;
  for (int i = t; i < 1024; i += 256)
    sP[i + (i >> 6)] = s2b[i];
  __syncthreads();

  const int pp = t >> 4, sub = t & 15;
  const float* ta = txyz + (n0 + pp * 2) * 3;
  const float a0 = ta[0], a1 = ta[1], a2 = ta[2];
  const float b0 = ta[3], b1 = ta[4], b2 = ta[5];
  const float q2a = __fadd_rn(__fadd_rn(__fmul_rn(a0, a0), __fmul_rn(a1, a1)), __fmul_rn(a2, a2));
  const float q2b = __fadd_rn(__fadd_rn(__fmul_rn(b0, b0), __fmul_rn(b1, b1)), __fmul_rn(b2, b2));

  float dA0 = 1e30f, dA1 = 1e30f, dA2 = 1e30f; int iA0 = 0, iA1 = 0, iA2 = 0;
  float dB0 = 1e30f, dB1 = 1e30f, dB2 = 1e30f; int iB0 = 0, iB1 = 0, iB2 = 0;
  float dC0 = 1e30f, dC1 = 1e30f, dC2 = 1e30f; int iC0 = 0, iC1 = 0, iC2 = 0;
  float dD0 = 1e30f, dD1 = 1e30f, dD2 = 1e30f; int iD0 = 0, iD1 = 0, iD2 = 0;
  const int sbeg = sub * 64;
  const float4* sA = sP + sbeg + (sbeg >> 6);

#pragma unroll 4
  for (int off = 0; off < 32; ++off) {
    const int s0 = sbeg + off;
    const int s1 = sbeg + 32 + off;
    float4 p0 = sA[off];
    float4 p1 = sA[32 + off];

    float c00 = __fmul_rn(a0, p0.x);
    c00 = __fadd_rn(c00, __fmul_rn(a1, p0.y));
    c00 = __fadd_rn(c00, __fmul_rn(a2, p0.z));
    float d00 = fmaxf(__fadd_rn(__fadd_rn(q2a, p0.w), -c00), 0.0f);

    float c01 = __fmul_rn(a0, p1.x);
    c01 = __fadd_rn(c01, __fmul_rn(a1, p1.y));
    c01 = __fadd_rn(c01, __fmul_rn(a2, p1.z));
    float d01 = fmaxf(__fadd_rn(__fadd_rn(q2a, p1.w), -c01), 0.0f);

    float c10 = __fmul_rn(b0, p0.x);
    c10 = __fadd_rn(c10, __fmul_rn(b1, p0.y));
    c10 = __fadd_rn(c10, __fmul_rn(b2, p0.z));
    float d10 = fmaxf(__fadd_rn(__fadd_rn(q2b, p0.w), -c10), 0.0f);

    float c11 = __fmul_rn(b0, p1.x);
    c11 = __fadd_rn(c11, __fmul_rn(b1, p1.y));
    c11 = __fadd_rn(c11, __fmul_rn(b2, p1.z));
    float d11 = fmaxf(__fadd_rn(__fadd_rn(q2b, p1.w), -c11), 0.0f);

    ins3m(d00, s0, dA0, dA1, dA2, iA0, iA1, iA2);
    ins3m(d01, s1, dB0, dB1, dB2, iB0, iB1, iB2);
    ins3m(d10, s0, dC0, dC1, dC2, iC0, iC1, iC2);
    ins3m(d11, s1, dD0, dD1, dD2, iD0, iD1, iD2);
  }
  ins3m(dB0, iB0, dA0, dA1, dA2, iA0, iA1, iA2);
  ins3m(dB1, iB1, dA0, dA1, dA2, iA0, iA1, iA2);
  ins3m(dB2, iB2, dA0, dA1, dA2, iA0, iA1, iA2);
  ins3m(dD0, iD0, dC0, dC1, dC2, iC0, iC1, iC2);
  ins3m(dD1, iD1, dC0, dC1, dC2, iC0, iC1, iC2);
  ins3m(dD2, iD2, dC0, dC1, dC2, iC0, iC1, iC2);

#pragma unroll
  for (int m = 1; m <= 8; m <<= 1) {
    merge_shfl(m, sub, dA0, dA1, dA2, iA0, iA1, iA2);
    merge_shfl(m, sub, dC0, dC1, dC2, iC0, iC1, iC2);
  }

  if (sub < 2) {
    const float tx = sub ? b0 : a0;
    const float ty = sub ? b1 : a1;
    const float tz = sub ? b2 : a2;
    const int   I0 = sub ? iC0 : iA0;
    const int   I1 = sub ? iC1 : iA1;
    const int   I2 = sub ? iC2 : iA2;
    int idxs[3] = {I0, I1, I2};
    float wv[3], wsum = 0.f;
    for (int k = 0; k < 3; ++k) {
      float4 sp = sP[idxs[k] + (idxs[k] >> 6)];
      float sx = 0.5f * sp.x, sy = 0.5f * sp.y, sz = 0.5f * sp.z;
      float dx = tx - sx, dy = ty - sy, dz = tz - sz;
      float dd = __fadd_rn(__fadd_rn(__fmul_rn(dx, dx), __fmul_rn(dy, dy)), __fmul_rn(dz, dz));
      wv[k] = 1.0f / (dd + 1e-8f);
      wsum += wv[k];
    }
    float inv = 1.0f / wsum;
    const int rr = pp * 2 + sub;
    nnbuf4[rr * 2 + 0] = make_float4(__int_as_float(I0), __int_as_float(I1), __int_as_float(I2), 0.f);
    nnbuf4[rr * 2 + 1] = make_float4(wv[0] * inv, wv[1] * inv, wv[2] * inv, 0.f);
  }
  __syncthreads();

  const int w = t >> 6, l = t & 63;
  {
    float4 my = nnbuf4[w * 16 + (l & 15)];
    const float4* fb4 = (const float4*)(sfeat + (size_t)b * 1024 * 256);
    const int r0 = w * 8;
#pragma unroll 4
    for (int r = 0; r < 8; ++r) {
      int j0 = __float_as_int(__shfl(my.x, 2 * r));
      int j1 = __float_as_int(__shfl(my.y, 2 * r));
      int j2 = __float_as_int(__shfl(my.z, 2 * r));
      float w0 = __shfl(my.x, 2 * r + 1);
      float w1 = __shfl(my.y, 2 * r + 1);
      float w2 = __shfl(my.z, 2 * r + 1);
      float4 A  = fb4[(size_t)j0 * 64 + l];
      float4 Bv = fb4[(size_t)j1 * 64 + l];
      float4 Cv = fb4[(size_t)j2 * 64 + l];
      ushort4 o;
      o.x = f2bf(w0 * A.x + w1 * Bv.x + w2 * Cv.x);
      o.y = f2bf(w0 * A.y + w1 * Bv.y + w2 * Cv.y);
      o.z = f2bf(w0 * A.z + w1 * Bv.z + w2 * Cv.z);
      o.w = f2bf(w0 * A.w + w1 * Bv.w + w2 * Cv.w);
      *(ushort4*)&As[(r0 + r) * 400 + 4 * l] = o;
    }
    const float4* sk4 = (const float4*)(skip + (n0 + r0) * 128);
#pragma unroll
    for (int it = 0; it < 4; ++it) {
      int rr = 2 * it + (l >> 5);
      int cc = l & 31;
      float4 s = sk4[it * 64 + l];
      ushort4 o;
      o.x = f2bf(s.x); o.y = f2bf(s.y); o.z = f2bf(s.z); o.w = f2bf(s.w);
      *(ushort4*)&As[(r0 + rr) * 400 + 256 + 4 * cc] = o;
    }
  }
  __syncthreads();

  const int wn = w;
  const int lm = l & 15, q = l >> 4;

  f32x4 acc[2][4] = {};
  const u16* Bf = W1f + (wn * 4) * 512 + l * 8;

#pragma unroll 4
  for (int kt = 0; kt < 12; ++kt) {
    bf16x8 af[2], bfv[4];
#pragma unroll
    for (int j = 0; j < 4; ++j)
      bfv[j] = *(const bf16x8*)(Bf + kt * 8192 + j * 512);
#pragma unroll
    for (int i = 0; i < 2; ++i)
      af[i] = *(const bf16x8*)&As[(i * 16 + lm) * 400 + kt * 32 + q * 8];
#pragma unroll
    for (int i = 0; i < 2; ++i)
#pragma unroll
      for (int j = 0; j < 4; ++j)
        acc[i][j] = __builtin_amdgcn_mfma_f32_16x16x32_bf16(af[i], bfv[j], acc[i][j], 0, 0, 0);
  }

  float lsum[4] = {0, 0, 0, 0}, lsq[4] = {0, 0, 0, 0};
  const int colb = wn * 64;
#pragma unroll
  for (int i = 0; i < 2; ++i) {
    const size_t mg = n0 + i * 16 + q * 4;
#pragma unroll
    for (int r = 0; r < 4; ++r) {
      const size_t ro = (mg + r) * 256;
#pragma unroll
      for (int j = 0; j < 4; ++j) {
        float v = acc[i][j][r];
        Y[ro + colb + j * 16 + lm] = f2bf(v);
        lsum[j] += v; lsq[j] += v * v;
      }
    }
  }
#pragma unroll
  for (int j = 0; j < 4; ++j) {
    lsum[j] += __shfl_xor(lsum[j], 16); lsum[j] += __shfl_xor(lsum[j], 32);
    lsq[j]  += __shfl_xor(lsq[j], 16);  lsq[j]  += __shfl_xor(lsq[j], 32);
  }
  if (q == 0) {
    float* bank = stats1 + (size_t)(raw & 7) * 512;
#pragma unroll
    for (int j = 0; j < 4; ++j) {
      atomicAdd(&bank[colb + j * 16 + lm], lsum[j]);
      atomicAdd(&bank[256 + colb + j * 16 + lm], lsq[j]);
    }
  }
}

__global__ __launch_bounds__(256) void gemm2f_kernel(
    const u16* __restrict__ Yin, const u16* __restrict__ W2f,
    const float* __restrict__ stats1, const float* __restrict__ g1,
    const float* __restrict__ be1, float* __restrict__ out,
    float* __restrict__ stats2) {
  __shared__ u16 As[32 * 272];
  __shared__ float a1s[256], b1s[256];
  __shared__ float csum[256], csq[256];

  const int t = threadIdx.x;
  const int bm = blockIdx.x;

  {
    float s = 0.f, sq = 0.f;
#pragma unroll
    for (int k = 0; k < 8; ++k) {
      s += stats1[k * 512 + t];
      sq += stats1[k * 512 + 256 + t];
    }
    const float invN = 1.0f / 65536.0f;
    float mean = s * invN;
    float var = sq * invN - mean * mean;
    float a = g1[t] * rsqrtf(var + 1e-5f);
    a1s[t] = a;
    b1s[t] = be1[t] - mean * a;
  }
  __syncthreads();

  const int w = t >> 6, l = t & 63;
  {
    const int r0 = w * 8;
#pragma unroll
    for (int it = 0; it < 4; ++it) {
      const int rr = r0 + 2 * it + (l >> 5);
      const int kb = (l & 31) * 8;
      uint4 rawv = *(const uint4*)(Yin + (size_t)(bm * 32 + rr) * 256 + kb);
      rawv = bnrelu_pack(rawv, a1s, b1s, kb);
      *(uint4*)&As[rr * 272 + kb] = rawv;
    }
  }
  __syncthreads();

  const int wm = w >> 1, wn = w & 1;
  const int lm = l & 15, q = l >> 4;

  f32x4 acc[4] = {};
  const u16* Bf = W2f + (wn * 4) * 512 + l * 8;

#pragma unroll 4
  for (int kt = 0; kt < 8; ++kt) {
    bf16x8 bfv[4];
#pragma unroll
    for (int j = 0; j < 4; ++j)
      bfv[j] = *(const bf16x8*)(Bf + kt * 4096 + j * 512);
    bf16x8 af = *(const bf16x8*)&As[(wm * 16 + lm) * 272 + kt * 32 + q * 8];
#pragma unroll
    for (int j = 0; j < 4; ++j)
      acc[j] = __builtin_amdgcn_mfma_f32_16x16x32_bf16(af, bfv[j], acc[j], 0, 0, 0);
  }

  float lsum[4] = {0, 0, 0, 0}, lsq[4] = {0, 0, 0, 0};
  const int colb = wn * 64;
  {
    const int mg = bm * 32 + wm * 16 + q * 4;
#pragma unroll
    for (int r = 0; r < 4; ++r) {
      const size_t ro = (size_t)(mg + r) * 128;
#pragma unroll
      for (int j = 0; j < 4; ++j) {
        float v = acc[j][r];
        out[ro + colb + j * 16 + lm] = v;
        lsum[j] += v; lsq[j] += v * v;
      }
    }
  }
#pragma unroll
  for (int j = 0; j < 4; ++j) {
    lsum[j] += __shfl_xor(lsum[j], 16); lsum[j] += __shfl_xor(lsum[j], 32);
    lsq[j]  += __shfl_xor(lsq[j], 16);  lsq[j]  += __shfl_xor(lsq[j], 32);
  }
  if (q == 0) {
    const int cell = wm * 128 + colb;
#pragma unroll
    for (int j = 0; j < 4; ++j) {
      csum[cell + j * 16 + lm] = lsum[j];
      csq[cell + j * 16 + lm] = lsq[j];
    }
  }
  __syncthreads();
  if (t < 128) {
    float* bank = stats2 + (size_t)(bm & 7) * 256;
    atomicAdd(&bank[t], csum[t] + csum[128 + t]);
    atomicAdd(&bank[128 + t], csq[t] + csq[128 + t]);
  }
}

__global__ __launch_bounds__(256) void bn_relu_out_kernel(
    float* __restrict__ out, const float* __restrict__ stats2,
    const float* __restrict__ g2, const float* __restrict__ be2) {
  __shared__ float a2[128], b2[128];
  int t = threadIdx.x;
  if (t < 128) {
    float s = 0.f, sq = 0.f;
#pragma unroll
    for (int k = 0; k < 8; ++k) {
      s += stats2[k * 256 + t];
      sq += stats2[k * 256 + 128 + t];
    }
    const float invN = 1.0f / 65536.0f;
    float mean = s * invN;
    float var = sq * invN - mean * mean;
    float a = g2[t] * rsqrtf(var + 1e-5f);
    a2[t] = a;
    b2[t] = be2[t] - mean * a;
  }
  __syncthreads();
  int idx = blockIdx.x * 256 + t;
  float4* o4 = (float4*)out;
  float4 v = o4[idx];
  int c = (idx * 4) & 127;
  v.x = fmaxf(v.x * a2[c + 0] + b2[c + 0], 0.f);
  v.y = fmaxf(v.y * a2[c + 1] + b2[c + 1], 0.f);
  v.z = fmaxf(v.z * a2[c + 2] + b2[c + 2], 0.f);
  v.w = fmaxf(v.w * a2[c + 3] + b2[c + 3], 0.f);
  o4[idx] = v;
}

extern "C" void kernel_launch(void* const* d_in, const int* in_sizes, int n_in,
                              void* d_out, int out_size, void* d_ws, size_t ws_size,
                              hipStream_t stream) {
  const float* txyz  = (const float*)d_in[0];
  const float* sxyz  = (const float*)d_in[1];
  const float* sfeat = (const float*)d_in[2];
  const float* skip  = (const float*)d_in[3];
  const float* W1    = (const float*)d_in[4];
  const float* g1    = (const float*)d_in[5];
  const float* be1   = (const float*)d_in[6];
  const float* W2    = (const float*)d_in[7];
  const float* g2    = (const float*)d_in[8];
  const float* be2   = (const float*)d_in[9];
  float* out = (float*)d_out;

  char* ws = (char*)d_ws;
  u16*    Y1  = (u16*)(ws + 0ull);                // 33554432 (fallback path only)
  u16*    W1f = (u16*)(ws + 33554432ull);         // 196608
  u16*    W2f = (u16*)(ws + 33751040ull);         // 65536
  float*  stats = (float*)(ws + 33816576ull);     // stats1[8][512] + stats2[8][256]
  float4* S2  = (float4*)(ws + 33841152ull);      // 262144

  float* stats1 = stats;
  float* stats2 = stats + 8 * 512;

  conv_w_kernel<<<512, 256, 0, stream>>>(W1, W2, sxyz, W1f, W2f, S2, stats);

  // Cooperative path requires all 2048 blocks co-resident (8/CU x 256 CUs).
  int occ = 0;
  hipError_t qerr = hipOccupancyMaxActiveBlocksPerMultiprocessor(&occ, mega_kernel, 256, 0);
  bool coop = (qerr == hipSuccess && occ >= 8);
  if (coop) {
    void* p_txyz = (void*)txyz;  void* p_S2 = (void*)S2;   void* p_sfeat = (void*)sfeat;
    void* p_skip = (void*)skip;  void* p_W1f = (void*)W1f; void* p_W2f = (void*)W2f;
    void* p_g1 = (void*)g1;      void* p_be1 = (void*)be1; void* p_g2 = (void*)g2;
    void* p_be2 = (void*)be2;    void* p_out = (void*)out; void* p_s1 = (void*)stats1;
    void* p_s2 = (void*)stats2;
    void* args[] = {&p_txyz, &p_S2, &p_sfeat, &p_skip, &p_W1f, &p_W2f,
                    &p_g1, &p_be1, &p_g2, &p_be2, &p_out, &p_s1, &p_s2};
    hipError_t lerr = hipLaunchCooperativeKernel(mega_kernel, dim3(2048), dim3(256),
                                                 args, 0u, stream);
    if (lerr != hipSuccess) coop = false;
  }
  if (!coop) {
    fused1_kernel<<<2048, 256, 0, stream>>>(txyz, S2, sfeat, skip, W1f, Y1, stats1);
    gemm2f_kernel<<<2048, 256, 0, stream>>>(Y1, W2f, stats1, g1, be1, out, stats2);
    bn_relu_out_kernel<<<8192, 256, 0, stream>>>(out, stats2, g2, be2);
  }
}

// Round 9
// 188.543 us; speedup vs baseline: 1.0182x; 1.0182x over previous
//
#include <hip/hip_runtime.h>

typedef unsigned short u16;
typedef unsigned int u32;

typedef __bf16 bf16x8 __attribute__((ext_vector_type(8)));
typedef float f32x4 __attribute__((ext_vector_type(4)));

__device__ __forceinline__ u16 f2bf(float f) {
  u32 u = __float_as_uint(f);
  u = u + 0x7fffu + ((u >> 16) & 1u);
  return (u16)(u >> 16);
}
__device__ __forceinline__ float bf2f(u16 u) {
  return __uint_as_float(((u32)u) << 16);
}

// strict-< top-3 insert: distances via min + 2x med3 (value-identical to the
// cndmask chain for finite inputs), indices via cmp+cndmask.
__device__ __forceinline__ void ins3m(float d, int s,
                                      float& d0, float& d1, float& d2,
                                      int& i0, int& i1, int& i2) {
  bool c0 = d < d0, c1 = d < d1, c2 = d < d2;
  float n0 = fminf(d, d0);
  float n1 = __builtin_amdgcn_fmed3f(d, d0, d1);
  float n2 = __builtin_amdgcn_fmed3f(d, d1, d2);
  i2 = c1 ? i1 : (c2 ? s : i2);
  i1 = c0 ? i0 : (c1 ? s : i1);
  i0 = c0 ? s : i0;
  d0 = n0; d1 = n1; d2 = n2;
}

// butterfly merge step across sub-lanes: lo-half list stays incumbent (its
// source indices are all smaller), hi-half sorted triple inserted in order ->
// strict-< keeps earliest index on ties, exactly like the sequential merge.
__device__ __forceinline__ void merge_shfl(int m, int sub,
                                           float& d0, float& d1, float& d2,
                                           int& i0, int& i1, int& i2) {
  float e0 = __shfl_xor(d0, m), e1 = __shfl_xor(d1, m), e2 = __shfl_xor(d2, m);
  int   f0 = __shfl_xor(i0, m), f1 = __shfl_xor(i1, m), f2 = __shfl_xor(i2, m);
  const bool up = (sub & m) != 0;
  float L0 = up ? e0 : d0, L1 = up ? e1 : d1, L2 = up ? e2 : d2;
  int   K0 = up ? f0 : i0, K1 = up ? f1 : i1, K2 = up ? f2 : i2;
  float H0 = up ? d0 : e0, H1 = up ? d1 : e1, H2 = up ? d2 : e2;
  int   G0 = up ? i0 : f0, G1 = up ? i1 : f1, G2 = up ? i2 : f2;
  ins3m(H0, G0, L0, L1, L2, K0, K1, K2);
  ins3m(H1, G1, L0, L1, L2, K0, K1, K2);
  ins3m(H2, G2, L0, L1, L2, K0, K1, K2);
  d0 = L0; d1 = L1; d2 = L2; i0 = K0; i1 = K1; i2 = K2;
}

__device__ __forceinline__ uint4 bnrelu_pack(uint4 raw, const float* a1s, const float* b1s, int kb) {
  union { uint4 v; u16 s[8]; } u;
  u.v = raw;
#pragma unroll
  for (int e = 0; e < 8; ++e) {
    float f = fmaxf(bf2f(u.s[e]) * a1s[kb + e] + b1s[kb + e], 0.f);
    u.s[e] = f2bf(f);
  }
  return u.v;
}

// ---------------------------------------------------------------- weights -> bf16 fragment order + S2 precompute + zero banked stats
// W1f layout: [kt=12][g=16][lane=64][e=8] : element = W1[g*16 + (l&15)][kt*32 + (l>>4)*8 + e]
// W2f layout: [kt= 8][g= 8][lane=64][e=8] : element = W2[g*16 + (l&15)][kt*32 + (l>>4)*8 + e]
// S2[b][s] = (2x,2y,2z,r2): doubling is exact -> d=(q2+r2)-dot(t,2s) is bit-identical
// to q2+r2-2*dot(t,s). stats: stats1[8][512] then stats2[8][256].
__global__ __launch_bounds__(256) void conv_w_kernel(
    const float* __restrict__ W1, const float* __restrict__ W2,
    const float* __restrict__ sxyz, u16* __restrict__ W1f,
    u16* __restrict__ W2f, float4* __restrict__ S2,
    float* __restrict__ stats) {
  int i = blockIdx.x * 256 + threadIdx.x;      // 512 * 256 = 131072 exactly
  if (i < 98304) {
    int e = i & 7, l = (i >> 3) & 63, g = (i >> 9) & 15, kt = i >> 13;
    int col = g * 16 + (l & 15);
    int k = kt * 32 + (l >> 4) * 8 + e;
    W1f[i] = f2bf(W1[col * 384 + k]);
  } else {
    int j = i - 98304;
    int e = j & 7, l = (j >> 3) & 63, g = (j >> 9) & 7, kt = j >> 12;
    int col = g * 16 + (l & 15);
    int k = kt * 32 + (l >> 4) * 8 + e;
    W2f[j] = f2bf(W2[col * 256 + k]);
  }
  if (i < 16384) {
    float x = sxyz[i * 3 + 0], y = sxyz[i * 3 + 1], z = sxyz[i * 3 + 2];
    float r2 = __fadd_rn(__fadd_rn(__fmul_rn(x, x), __fmul_rn(y, y)), __fmul_rn(z, z));
    S2[i] = make_float4(x + x, y + y, z + z, r2);
  }
  if (i < 6144) stats[i] = 0.f;
}

// ---------------------------------------------------------------- FUSED 3NN + gather + concat + GEMM1  (round-7 proven, 70us)
// 2048 blocks x 256 threads, XCD-swizzled; LDS 26624B -> 6 blocks/CU.
__global__ __launch_bounds__(256, 6) void fused1_kernel(
    const float* __restrict__ txyz, const float4* __restrict__ S2,
    const float* __restrict__ sfeat, const float* __restrict__ skip,
    const u16* __restrict__ W1f, u16* __restrict__ Y,
    float* __restrict__ stats1) {
  __shared__ __align__(16) char smem[26624];
  u16*    As     = (u16*)smem;                 // 32*400*2 = 25600 (phase 2/3)
  float4* sP     = (float4*)smem;              // 1040*16 = 16640 (phase 1)
  float4* nnbuf4 = (float4*)(smem + 25600);    // 64*16 = 1024

  const int t = threadIdx.x;
  const int raw = blockIdx.x;
  const int logical = (raw & 7) * 256 + (raw >> 3);   // bijective, 2048 = 8*256
  const int b = logical >> 7;
  const int pg = logical & 127;
  const size_t n0 = (size_t)b * 4096 + (size_t)pg * 32;

  // ---- phase 0: copy precomputed (2x,2y,2z,r2) into LDS
  const float4* s2b = S2 + (size_t)b * 1024;
  for (int i = t; i < 1024; i += 256)
    sP[i + (i >> 6)] = s2b[i];
  __syncthreads();

  // ---- phase 1: 3NN scan (2 pts/thread x 16 sub-scans of 64; dual streams)
  const int pp = t >> 4, sub = t & 15;
  const float* ta = txyz + (n0 + pp * 2) * 3;
  const float a0 = ta[0], a1 = ta[1], a2 = ta[2];
  const float b0 = ta[3], b1 = ta[4], b2 = ta[5];
  const float q2a = __fadd_rn(__fadd_rn(__fmul_rn(a0, a0), __fmul_rn(a1, a1)), __fmul_rn(a2, a2));
  const float q2b = __fadd_rn(__fadd_rn(__fmul_rn(b0, b0), __fmul_rn(b1, b1)), __fmul_rn(b2, b2));

  float dA0 = 1e30f, dA1 = 1e30f, dA2 = 1e30f; int iA0 = 0, iA1 = 0, iA2 = 0;
  float dB0 = 1e30f, dB1 = 1e30f, dB2 = 1e30f; int iB0 = 0, iB1 = 0, iB2 = 0;
  float dC0 = 1e30f, dC1 = 1e30f, dC2 = 1e30f; int iC0 = 0, iC1 = 0, iC2 = 0;
  float dD0 = 1e30f, dD1 = 1e30f, dD2 = 1e30f; int iD0 = 0, iD1 = 0, iD2 = 0;
  const int sbeg = sub * 64;
  const float4* sA = sP + sbeg + (sbeg >> 6);

#pragma unroll 4
  for (int off = 0; off < 32; ++off) {
    const int s0 = sbeg + off;
    const int s1 = sbeg + 32 + off;
    float4 p0 = sA[off];
    float4 p1 = sA[32 + off];

    float c00 = __fmul_rn(a0, p0.x);
    c00 = __fadd_rn(c00, __fmul_rn(a1, p0.y));
    c00 = __fadd_rn(c00, __fmul_rn(a2, p0.z));
    float d00 = fmaxf(__fadd_rn(__fadd_rn(q2a, p0.w), -c00), 0.0f);

    float c01 = __fmul_rn(a0, p1.x);
    c01 = __fadd_rn(c01, __fmul_rn(a1, p1.y));
    c01 = __fadd_rn(c01, __fmul_rn(a2, p1.z));
    float d01 = fmaxf(__fadd_rn(__fadd_rn(q2a, p1.w), -c01), 0.0f);

    float c10 = __fmul_rn(b0, p0.x);
    c10 = __fadd_rn(c10, __fmul_rn(b1, p0.y));
    c10 = __fadd_rn(c10, __fmul_rn(b2, p0.z));
    float d10 = fmaxf(__fadd_rn(__fadd_rn(q2b, p0.w), -c10), 0.0f);

    float c11 = __fmul_rn(b0, p1.x);
    c11 = __fadd_rn(c11, __fmul_rn(b1, p1.y));
    c11 = __fadd_rn(c11, __fmul_rn(b2, p1.z));
    float d11 = fmaxf(__fadd_rn(__fadd_rn(q2b, p1.w), -c11), 0.0f);

    ins3m(d00, s0, dA0, dA1, dA2, iA0, iA1, iA2);
    ins3m(d01, s1, dB0, dB1, dB2, iB0, iB1, iB2);
    ins3m(d10, s0, dC0, dC1, dC2, iC0, iC1, iC2);
    ins3m(d11, s1, dD0, dD1, dD2, iD0, iD1, iD2);
  }
  ins3m(dB0, iB0, dA0, dA1, dA2, iA0, iA1, iA2);
  ins3m(dB1, iB1, dA0, dA1, dA2, iA0, iA1, iA2);
  ins3m(dB2, iB2, dA0, dA1, dA2, iA0, iA1, iA2);
  ins3m(dD0, iD0, dC0, dC1, dC2, iC0, iC1, iC2);
  ins3m(dD1, iD1, dC0, dC1, dC2, iC0, iC1, iC2);
  ins3m(dD2, iD2, dC0, dC1, dC2, iC0, iC1, iC2);

#pragma unroll
  for (int m = 1; m <= 8; m <<= 1) {
    merge_shfl(m, sub, dA0, dA1, dA2, iA0, iA1, iA2);
    merge_shfl(m, sub, dC0, dC1, dC2, iC0, iC1, iC2);
  }

  if (sub < 2) {
    const float tx = sub ? b0 : a0;
    const float ty = sub ? b1 : a1;
    const float tz = sub ? b2 : a2;
    const int   I0 = sub ? iC0 : iA0;
    const int   I1 = sub ? iC1 : iA1;
    const int   I2 = sub ? iC2 : iA2;
    int idxs[3] = {I0, I1, I2};
    float wv[3], wsum = 0.f;
    for (int k = 0; k < 3; ++k) {
      float4 sp = sP[idxs[k] + (idxs[k] >> 6)];
      float sx = 0.5f * sp.x, sy = 0.5f * sp.y, sz = 0.5f * sp.z;  // exact halving
      float dx = tx - sx, dy = ty - sy, dz = tz - sz;
      float dd = __fadd_rn(__fadd_rn(__fmul_rn(dx, dx), __fmul_rn(dy, dy)), __fmul_rn(dz, dz));
      wv[k] = 1.0f / (dd + 1e-8f);
      wsum += wv[k];
    }
    float inv = 1.0f / wsum;
    const int rr = pp * 2 + sub;
    nnbuf4[rr * 2 + 0] = make_float4(__int_as_float(I0), __int_as_float(I1), __int_as_float(I2), 0.f);
    nnbuf4[rr * 2 + 1] = make_float4(wv[0] * inv, wv[1] * inv, wv[2] * inv, 0.f);
  }
  __syncthreads();   // sP reads + nnbuf writes complete; As may overwrite sP

  // ---- phase 2: wave-coalesced staging; wave w stages rows 8w..8w+7
  const int w = t >> 6, l = t & 63;
  {
    float4 my = nnbuf4[w * 16 + (l & 15)];
    const float4* fb4 = (const float4*)(sfeat + (size_t)b * 1024 * 256);
    const int r0 = w * 8;
#pragma unroll 4
    for (int r = 0; r < 8; ++r) {
      int j0 = __float_as_int(__shfl(my.x, 2 * r));
      int j1 = __float_as_int(__shfl(my.y, 2 * r));
      int j2 = __float_as_int(__shfl(my.z, 2 * r));
      float w0 = __shfl(my.x, 2 * r + 1);
      float w1 = __shfl(my.y, 2 * r + 1);
      float w2 = __shfl(my.z, 2 * r + 1);
      float4 A  = fb4[(size_t)j0 * 64 + l];
      float4 Bv = fb4[(size_t)j1 * 64 + l];
      float4 Cv = fb4[(size_t)j2 * 64 + l];
      ushort4 o;
      o.x = f2bf(w0 * A.x + w1 * Bv.x + w2 * Cv.x);
      o.y = f2bf(w0 * A.y + w1 * Bv.y + w2 * Cv.y);
      o.z = f2bf(w0 * A.z + w1 * Bv.z + w2 * Cv.z);
      o.w = f2bf(w0 * A.w + w1 * Bv.w + w2 * Cv.w);
      *(ushort4*)&As[(r0 + r) * 400 + 4 * l] = o;
    }
    const float4* sk4 = (const float4*)(skip + (n0 + r0) * 128);
#pragma unroll
    for (int it = 0; it < 4; ++it) {
      int rr = 2 * it + (l >> 5);
      int cc = l & 31;
      float4 s = sk4[it * 64 + l];
      ushort4 o;
      o.x = f2bf(s.x); o.y = f2bf(s.y); o.z = f2bf(s.z); o.w = f2bf(s.w);
      *(ushort4*)&As[(r0 + rr) * 400 + 256 + 4 * cc] = o;
    }
  }
  __syncthreads();

  // ---- phase 3: barrier-free K-loop; wave w owns cols w*64..w*64+63
  const int wn = w;
  const int lm = l & 15, q = l >> 4;

  f32x4 acc[2][4] = {};
  const u16* Bf = W1f + (wn * 4) * 512 + l * 8;

#pragma unroll 4
  for (int kt = 0; kt < 12; ++kt) {
    bf16x8 af[2], bfv[4];
#pragma unroll
    for (int j = 0; j < 4; ++j)
      bfv[j] = *(const bf16x8*)(Bf + kt * 8192 + j * 512);
#pragma unroll
    for (int i = 0; i < 2; ++i)
      af[i] = *(const bf16x8*)&As[(i * 16 + lm) * 400 + kt * 32 + q * 8];
#pragma unroll
    for (int i = 0; i < 2; ++i)
#pragma unroll
      for (int j = 0; j < 4; ++j)
        acc[i][j] = __builtin_amdgcn_mfma_f32_16x16x32_bf16(af[i], bfv[j], acc[i][j], 0, 0, 0);
  }

  // ---- epilogue: bf16 Y1 + column stats (shfl over q -> direct banked atomics)
  float lsum[4] = {0, 0, 0, 0}, lsq[4] = {0, 0, 0, 0};
  const int colb = wn * 64;
#pragma unroll
  for (int i = 0; i < 2; ++i) {
    const size_t mg = n0 + i * 16 + q * 4;
#pragma unroll
    for (int r = 0; r < 4; ++r) {
      const size_t ro = (mg + r) * 256;
#pragma unroll
      for (int j = 0; j < 4; ++j) {
        float v = acc[i][j][r];
        Y[ro + colb + j * 16 + lm] = f2bf(v);
        lsum[j] += v; lsq[j] += v * v;
      }
    }
  }
#pragma unroll
  for (int j = 0; j < 4; ++j) {
    lsum[j] += __shfl_xor(lsum[j], 16); lsum[j] += __shfl_xor(lsum[j], 32);
    lsq[j]  += __shfl_xor(lsq[j], 16);  lsq[j]  += __shfl_xor(lsq[j], 32);
  }
  if (q == 0) {
    float* bank = stats1 + (size_t)(raw & 7) * 512;
#pragma unroll
    for (int j = 0; j < 4; ++j) {
      atomicAdd(&bank[colb + j * 16 + lm], lsum[j]);
      atomicAdd(&bank[256 + colb + j * 16 + lm], lsq[j]);
    }
  }
}

// ---------------------------------------------------------------- GEMM2: out = relu(bn1(Y1)) * W2^T
// XCD-chained: same bijective swizzle as fused1, so block raw reads the Y1
// rows that fused1's block raw (same XCD raw&7) wrote -> Y1 reads hit the
// local XCD L2 (4.2MB/XCD) instead of HBM. Out writes land as one contiguous
// 8192-row chunk per XCD, which bn_relu_out's mapping exploits.
__global__ __launch_bounds__(256) void gemm2f_kernel(
    const u16* __restrict__ Yin, const u16* __restrict__ W2f,
    const float* __restrict__ stats1, const float* __restrict__ g1,
    const float* __restrict__ be1, float* __restrict__ out,
    float* __restrict__ stats2) {
  __shared__ u16 As[32 * 272];
  __shared__ float a1s[256], b1s[256];
  __shared__ float csum[256], csq[256];

  const int t = threadIdx.x;
  const int raw = blockIdx.x;
  const int bm = (raw & 7) * 256 + (raw >> 3);   // same bijection as fused1

  // BN1 finalize in-block: sum the 8 banks, then a/b
  {
    float s = 0.f, sq = 0.f;
#pragma unroll
    for (int k = 0; k < 8; ++k) {
      s += stats1[k * 512 + t];
      sq += stats1[k * 512 + 256 + t];
    }
    const float invN = 1.0f / 65536.0f;
    float mean = s * invN;
    float var = sq * invN - mean * mean;
    float a = g1[t] * rsqrtf(var + 1e-5f);
    a1s[t] = a;
    b1s[t] = be1[t] - mean * a;
  }
  __syncthreads();

  // ---- stage A with fused bn1+relu; wave w stages rows 8w..8w+7 (1KB/instr)
  const int w = t >> 6, l = t & 63;
  {
    const int r0 = w * 8;
#pragma unroll
    for (int it = 0; it < 4; ++it) {
      const int rr = r0 + 2 * it + (l >> 5);
      const int kb = (l & 31) * 8;
      uint4 rawv = *(const uint4*)(Yin + (size_t)(bm * 32 + rr) * 256 + kb);
      rawv = bnrelu_pack(rawv, a1s, b1s, kb);
      *(uint4*)&As[rr * 272 + kb] = rawv;
    }
  }
  __syncthreads();

  const int wm = w >> 1, wn = w & 1;       // wave grid 2x2: 16 rows x 64 cols each
  const int lm = l & 15, q = l >> 4;

  f32x4 acc[4] = {};
  const u16* Bf = W2f + (wn * 4) * 512 + l * 8;

#pragma unroll 4
  for (int kt = 0; kt < 8; ++kt) {
    bf16x8 bfv[4];
#pragma unroll
    for (int j = 0; j < 4; ++j)
      bfv[j] = *(const bf16x8*)(Bf + kt * 4096 + j * 512);
    bf16x8 af = *(const bf16x8*)&As[(wm * 16 + lm) * 272 + kt * 32 + q * 8];
#pragma unroll
    for (int j = 0; j < 4; ++j)
      acc[j] = __builtin_amdgcn_mfma_f32_16x16x32_bf16(af, bfv[j], acc[j], 0, 0, 0);
  }

  float lsum[4] = {0, 0, 0, 0}, lsq[4] = {0, 0, 0, 0};
  const int colb = wn * 64;
  {
    const int mg = bm * 32 + wm * 16 + q * 4;
#pragma unroll
    for (int r = 0; r < 4; ++r) {
      const size_t ro = (size_t)(mg + r) * 128;
#pragma unroll
      for (int j = 0; j < 4; ++j) {
        float v = acc[j][r];
        out[ro + colb + j * 16 + lm] = v;
        lsum[j] += v; lsq[j] += v * v;
      }
    }
  }
#pragma unroll
  for (int j = 0; j < 4; ++j) {
    lsum[j] += __shfl_xor(lsum[j], 16); lsum[j] += __shfl_xor(lsum[j], 32);
    lsq[j]  += __shfl_xor(lsq[j], 16);  lsq[j]  += __shfl_xor(lsq[j], 32);
  }
  if (q == 0) {
    const int cell = wm * 128 + colb;      // unique per (wm,wn,j,lm): plain store
#pragma unroll
    for (int j = 0; j < 4; ++j) {
      csum[cell + j * 16 + lm] = lsum[j];
      csq[cell + j * 16 + lm] = lsq[j];
    }
  }
  __syncthreads();
  if (t < 128) {
    float* bank = stats2 + (size_t)(raw & 7) * 256;
    atomicAdd(&bank[t], csum[t] + csum[128 + t]);
    atomicAdd(&bank[128 + t], csq[t] + csq[128 + t]);
  }
}

// ---------------------------------------------------------------- final BN2+ReLU in place on d_out
// XCD-chained read: gemm2f (swizzled) wrote out rows [x*8192,(x+1)*8192) from
// XCD x. Block j here runs on XCD j&7 and processes rows inside that same
// chunk -> reads served by the local XCD L2.
__global__ __launch_bounds__(256) void bn_relu_out_kernel(
    float* __restrict__ out, const float* __restrict__ stats2,
    const float* __restrict__ g2, const float* __restrict__ be2) {
  __shared__ float a2[128], b2[128];
  int t = threadIdx.x;
  if (t < 128) {
    float s = 0.f, sq = 0.f;
#pragma unroll
    for (int k = 0; k < 8; ++k) {
      s += stats2[k * 256 + t];
      sq += stats2[k * 256 + 128 + t];
    }
    const float invN = 1.0f / 65536.0f;
    float mean = s * invN;
    float var = sq * invN - mean * mean;
    float a = g2[t] * rsqrtf(var + 1e-5f);
    a2[t] = a;
    b2[t] = be2[t] - mean * a;
  }
  __syncthreads();
  const int j = blockIdx.x;                   // 8192 blocks
  const int xcd = j & 7, k = j >> 3;          // chunk xcd, 1024 sub-blocks each
  const int idx = xcd * 262144 + k * 256 + t; // 8 rows (256 float4) per block
  float4* o4 = (float4*)out;
  float4 v = o4[idx];
  int c = (idx * 4) & 127;
  v.x = fmaxf(v.x * a2[c + 0] + b2[c + 0], 0.f);
  v.y = fmaxf(v.y * a2[c + 1] + b2[c + 1], 0.f);
  v.z = fmaxf(v.z * a2[c + 2] + b2[c + 2], 0.f);
  v.w = fmaxf(v.w * a2[c + 3] + b2[c + 3], 0.f);
  o4[idx] = v;
}

extern "C" void kernel_launch(void* const* d_in, const int* in_sizes, int n_in,
                              void* d_out, int out_size, void* d_ws, size_t ws_size,
                              hipStream_t stream) {
  const float* txyz  = (const float*)d_in[0];
  const float* sxyz  = (const float*)d_in[1];
  const float* sfeat = (const float*)d_in[2];
  const float* skip  = (const float*)d_in[3];
  const float* W1    = (const float*)d_in[4];
  const float* g1    = (const float*)d_in[5];
  const float* be1   = (const float*)d_in[6];
  const float* W2    = (const float*)d_in[7];
  const float* g2    = (const float*)d_in[8];
  const float* be2   = (const float*)d_in[9];
  float* out = (float*)d_out;

  char* ws = (char*)d_ws;
  u16*    Y1  = (u16*)(ws + 0ull);                // 65536*256*2 = 33554432
  u16*    W1f = (u16*)(ws + 33554432ull);         // 196608
  u16*    W2f = (u16*)(ws + 33751040ull);         // 65536
  float*  stats = (float*)(ws + 33816576ull);     // stats1[8][512] + stats2[8][256]
  float4* S2  = (float4*)(ws + 33841152ull);      // 262144

  float* stats1 = stats;
  float* stats2 = stats + 8 * 512;

  conv_w_kernel<<<512, 256, 0, stream>>>(W1, W2, sxyz, W1f, W2f, S2, stats);
  fused1_kernel<<<2048, 256, 0, stream>>>(txyz, S2, sfeat, skip, W1f, Y1, stats1);
  gemm2f_kernel<<<2048, 256, 0, stream>>>(Y1, W2f, stats1, g1, be1, out, stats2);
  bn_relu_out_kernel<<<8192, 256, 0, stream>>>(out, stats2, g2, be2);
}